// Round 1
// baseline (1606.548 us; speedup 1.0000x reference)
//
#include <hip/hip_runtime.h>

// out[B,64] = x[B,64] @ W[:, :64]^T + b   (W stored [64][128] row-major, fp32)
//
// Mapping: lane h (0..63) owns output column h and holds W[h][0:64] in 64 VGPRs
// (pinned via opaque asm so the compiler cannot rematerialize the loads -- the
// previous version's VGPR_Count=60 proved W was being re-fetched every tile).
//
// The broadcast x operand is wave-uniform, so it is fed from SGPRs via
// s_load_dwordx16 (scalar pipe, 64B written once) instead of LDS broadcast
// ds_read_b128 (which costs ~6 cyc each on the single per-CU LDS pipe and was
// the measured bottleneck: 1024 tiles/CU * 128 reads * 6 cyc = 327 us ~ 337 us).
// v_fmac_f32 vdst, s, v takes one SGPR source, which is exactly this pattern.
//
// No LDS, no barriers. Per row: 4 s_load_dwordx16 (prefetching the NEXT row,
// issued chunk-by-chunk right after the current chunk's FMAs, so the loads get
// a ~130-cycle head start) + 64 v_fmac + one 256B coalesced store.

typedef __attribute__((ext_vector_type(16))) float f32x16;
typedef __attribute__((ext_vector_type(4)))  float f32x4;

#define WAVES_PER_BLOCK 4
#define GRID_BLOCKS 1536   // 6 blocks/CU * 256 CU; 6144 waves, ~341 rows/wave

__global__ __launch_bounds__(256, 6)
void hmsrl_kernel(const float* __restrict__ x, const float* __restrict__ W,
                  const float* __restrict__ b, float* __restrict__ out, int B) {
    const int lane = threadIdx.x & 63;

    // ---- W row for this lane's output column: 16 x float4 = 64 VGPRs ----
    const f32x4* wrow = reinterpret_cast<const f32x4*>(W + lane * 128);
    f32x4 w[16];
    #pragma unroll
    for (int j = 0; j < 16; ++j) w[j] = wrow[j];
    // Pin: opaque asm makes the values unrematerializable -> stays in VGPRs.
    #pragma unroll
    for (int j = 0; j < 16; ++j) asm volatile("" : "+v"(w[j]));
    const float bias = b[lane];

    int wid = blockIdx.x * WAVES_PER_BLOCK + (threadIdx.x >> 6);
    wid = __builtin_amdgcn_readfirstlane(wid);          // force uniform/SALU
    const int nw = gridDim.x * WAVES_PER_BLOCK;

    const float* xp = x + (size_t)wid * 64;             // uniform row pointer
    float*       op = out + (size_t)wid * 64;           // uniform out-row base
    const size_t xstep = (size_t)nw * 64;

    // Four 16-float chunks of the current row, resident in 64 SGPRs.
    f32x16 c0, c1, c2, c3;

    // Prologue: load row `wid`.
    asm volatile("s_load_dwordx16 %0, %1, 0x00" : "+s"(c0) : "s"(xp));
    asm volatile("s_load_dwordx16 %0, %1, 0x40" : "+s"(c1) : "s"(xp));
    asm volatile("s_load_dwordx16 %0, %1, 0x80" : "+s"(c2) : "s"(xp));
    asm volatile("s_load_dwordx16 %0, %1, 0xc0" : "+s"(c3) : "s"(xp));

    for (int row = wid; row < B; row += nw) {
        // Next row to prefetch (clamped to x base on the last iteration so we
        // never issue an out-of-bounds s_load).
        const float* xn = (row + nw < B) ? (xp + xstep) : x;

        // SMEM results can retire out of order -> wait all four chunks.
        // The "+s" operand list creates true deps: every consumer FMA is
        // ordered after this wait, every producer load before it.
        asm volatile("s_waitcnt lgkmcnt(0)"
                     : "+s"(c0), "+s"(c1), "+s"(c2), "+s"(c3));

        float acc = bias;
        #pragma unroll
        for (int j = 0; j < 16; ++j)
            acc = fmaf(c0[j], w[j >> 2][j & 3], acc);
        asm volatile("s_load_dwordx16 %0, %1, 0x00" : "+s"(c0) : "s"(xn));

        #pragma unroll
        for (int j = 0; j < 16; ++j)
            acc = fmaf(c1[j], w[4 + (j >> 2)][j & 3], acc);
        asm volatile("s_load_dwordx16 %0, %1, 0x40" : "+s"(c1) : "s"(xn));

        #pragma unroll
        for (int j = 0; j < 16; ++j)
            acc = fmaf(c2[j], w[8 + (j >> 2)][j & 3], acc);
        asm volatile("s_load_dwordx16 %0, %1, 0x80" : "+s"(c2) : "s"(xn));

        #pragma unroll
        for (int j = 0; j < 16; ++j)
            acc = fmaf(c3[j], w[12 + (j >> 2)][j & 3], acc);
        asm volatile("s_load_dwordx16 %0, %1, 0xc0" : "+s"(c3) : "s"(xn));

        // ---- store: 256 B coalesced (lane h -> col h of contiguous row) ----
        op[lane] = acc;

        xp = xn;
        op += xstep;
    }
}

extern "C" void kernel_launch(void* const* d_in, const int* in_sizes, int n_in,
                              void* d_out, int out_size, void* d_ws, size_t ws_size,
                              hipStream_t stream) {
    const float* x = (const float*)d_in[0];
    const float* W = (const float*)d_in[1];
    const float* b = (const float*)d_in[2];
    float* out     = (float*)d_out;

    const int B = in_sizes[0] / 64;     // 2,097,152

    hmsrl_kernel<<<GRID_BLOCKS, 256, 0, stream>>>(x, W, b, out, B);
}